// Round 3
// baseline (275.241 us; speedup 1.0000x reference)
//
#include <hip/hip_runtime.h>
#include <stdint.h>

// Problem constants
#define NLAYERS 32
#define DSIZE   1024
#define OSIZE   1024
#define BATCH   32
#define SEQ     256

// ws layout (ints): [0]=nchunks; [16..272)=perm; [512 + 4*c ..]=chunk{layer, rank_base, nranks, pad}
#define WS_PERM  16
#define WS_TILE  512
#define CHUNK    8      // seq positions per m-chunk -> 256 m-rows (8 ranks x 32 batch)
#define BK       32
#define TM       256
#define TN       128
#define THREADS  512
#define KITERS   (DSIZE / BK)   // 32

typedef __attribute__((ext_vector_type(8)))  short short8;
typedef __attribute__((ext_vector_type(16))) float f32x16;
typedef __attribute__((ext_vector_type(4)))  unsigned uint4v;

__global__ void prep_kernel(const int* __restrict__ layer_idx, int* __restrict__ wsi) {
    __shared__ int cnt[NLAYERS];
    __shared__ int start_[NLAYERS];
    __shared__ int cursor[NLAYERS];
    const int t = threadIdx.x;
    if (t < NLAYERS) cnt[t] = 0;
    __syncthreads();
    int l = 0;
    if (t < SEQ) { l = layer_idx[t]; atomicAdd(&cnt[l], 1); }
    __syncthreads();
    if (t == 0) {
        int acc = 0;
        for (int i = 0; i < NLAYERS; ++i) { start_[i] = acc; cursor[i] = acc; acc += cnt[i]; }
    }
    __syncthreads();
    if (t < SEQ) {
        int r = atomicAdd(&cursor[l], 1);
        wsi[WS_PERM + r] = t;           // perm[rank] = s
    }
    if (t == 0) {
        int nc = 0;
        for (int i = 0; i < NLAYERS; ++i) {
            const int c = cnt[i];
            for (int j = 0; j < c; j += CHUNK) {
                wsi[WS_TILE + nc*4 + 0] = i;
                wsi[WS_TILE + nc*4 + 1] = start_[i] + j;
                wsi[WS_TILE + nc*4 + 2] = (c - j < CHUNK) ? (c - j) : CHUNK;
                ++nc;
            }
        }
        wsi[0] = nc;   // <= 60
    }
}

// round-to-nearest-up fp32->bf16 pair pack: low16 = bf16(a), high16 = bf16(b)
static __device__ __forceinline__ unsigned pk2(float a, float b) {
    unsigned ua = __builtin_bit_cast(unsigned, a) + 0x8000u;
    unsigned ub = __builtin_bit_cast(unsigned, b) + 0x8000u;
    return __builtin_amdgcn_perm(ub, ua, 0x07060302u);  // {ua[2],ua[3],ub[2],ub[3]}
}

// Tile: 256 m-rows (8 ranks x 32 batch) x 128 o-cols, BK=32, 8 waves (4m x 2n),
// wave tile 64m x 64n, acc = 2x2 of 32x32 (64 AGPR). Stage regs 24 -> ~110 total
// -> 4 waves/SIMD tier; LDS 48KB double-buffered -> 2 blocks/CU = 16 waves/CU.
// LDS row = 32 bf16 (64B) = 4 granules of 16B; granule g of row r stored at
// position g ^ (r&3)  -> min-cycle ds_write_b128 / ds_read_b128 (8 cyc/wave-instr).
// K-loop: double buffer, ONE barrier per iter: issue loads(k+1) -> MFMA buf[cur]
// -> pk2+write buf[cur^1] -> barrier. vmcnt naturally ~0 at barrier (no drain stall).
// Grid 512: fid&7 = XCD = g&7; all 8 n-tiles of chunk g on one XCD -> A-slab (1MB)
// re-reads hit that XCD's L2.
__global__ __launch_bounds__(THREADS, 4) void gemm_kernel(
        const float* __restrict__ x, const float* __restrict__ wgt,
        const int* __restrict__ wsi, float* __restrict__ out) {
    const int fid = blockIdx.x;
    const int xcd = fid & 7;
    const int u   = fid >> 3;                 // 0..63
    const int g   = ((u >> 3) << 3) | xcd;    // chunk 0..63
    const int ntile = u & 7;                  // o block of 128
    const int nchunks = wsi[0];
    if (g >= nchunks) return;
    const int layer     = wsi[WS_TILE + g*4 + 0];
    const int rank_base = wsi[WS_TILE + g*4 + 1];
    const int nranks    = wsi[WS_TILE + g*4 + 2];      // 1..8

    __shared__ __align__(16) short ldsA[2][TM * BK];
    __shared__ __align__(16) short ldsB[2][TN * BK];

    const int t    = threadIdx.x;
    // ---- staging mapping: slot = 16B LDS granule (8 k-elems = 32B fp32 source)
    const int slot = t & 3;
    const int rb   = t >> 2;          // 0..127
    const int wsw  = ((slot ^ (rb & 3)) << 3);   // swizzled granule offset (shorts)

    const float* aptr[2];
    bool av[2];
    #pragma unroll
    for (int p = 0; p < 2; ++p) {
        const int r  = rb + 128*p;
        const int ro = r >> 5;        // rank 0..7
        const int b  = r & 31;        // batch
        av[p] = (ro < nranks);
        const int s = av[p] ? wsi[WS_PERM + rank_base + ro] : 0;
        aptr[p] = x + (((size_t)(b * SEQ + s)) << 10) + slot*8;
    }
    const float* bptr = wgt + ((size_t)layer << 20)
                            + (((size_t)(ntile * TN + rb)) << 10) + slot*8;

    float4 ra[2][2], rbv[2];
    auto load_step = [&](int kk) {
        #pragma unroll
        for (int p = 0; p < 2; ++p) {
            if (av[p]) {
                ra[p][0] = *(const float4*)(aptr[p] + kk);
                ra[p][1] = *(const float4*)(aptr[p] + kk + 4);
            }
        }
        rbv[0] = *(const float4*)(bptr + kk);
        rbv[1] = *(const float4*)(bptr + kk + 4);
    };
    auto store_to = [&](int buf) {
        #pragma unroll
        for (int p = 0; p < 2; ++p) {
            if (av[p]) {
                uint4v u4;
                u4.x = pk2(ra[p][0].x, ra[p][0].y);
                u4.y = pk2(ra[p][0].z, ra[p][0].w);
                u4.z = pk2(ra[p][1].x, ra[p][1].y);
                u4.w = pk2(ra[p][1].z, ra[p][1].w);
                *(uint4v*)&ldsA[buf][(rb + 128*p) * BK + wsw] = u4;
            }
        }
        {
            uint4v u4;
            u4.x = pk2(rbv[0].x, rbv[0].y);
            u4.y = pk2(rbv[0].z, rbv[0].w);
            u4.z = pk2(rbv[1].x, rbv[1].y);
            u4.w = pk2(rbv[1].z, rbv[1].w);
            *(uint4v*)&ldsB[buf][rb * BK + wsw] = u4;
        }
    };

    // ---- compute mapping: 8 waves as 4(m) x 2(n), wave tile 64x64
    const int lane = t & 63;
    const int wv   = t >> 6;
    const int l31  = lane & 31;
    const int lh   = lane >> 5;
    const int wm   = (wv >> 1) << 6;   // 0,64,128,192
    const int wn   = (wv & 1) << 6;    // 0,64
    const int rsw  = l31 & 3;          // read-side swizzle (row & 3)

    const int baseA0 = (wm +  0 + l31) * BK;
    const int baseA1 = (wm + 32 + l31) * BK;
    const int baseB0 = (wn +  0 + l31) * BK;
    const int baseB1 = (wn + 32 + l31) * BK;

    const int rank0 = wm >> 5;
    const bool ok0 = (rank0 + 0) < nranks;
    const bool ok1 = (rank0 + 1) < nranks;

    f32x16 acc[2][2];
    #pragma unroll
    for (int mi = 0; mi < 2; ++mi)
        #pragma unroll
        for (int ni = 0; ni < 2; ++ni)
            #pragma unroll
            for (int r = 0; r < 16; ++r) acc[mi][ni][r] = 0.f;

    // prologue: fill buf0
    load_step(0);
    store_to(0);
    __syncthreads();

    #pragma unroll 1
    for (int kt = 0; kt < KITERS; ++kt) {
        const int cur = kt & 1;
        const bool more = (kt + 1 < KITERS);
        if (more) load_step((kt + 1) * BK);   // issue early; lands during MFMA
        #pragma unroll
        for (int sub = 0; sub < 2; ++sub) {
            const int gx = (((sub << 1) | lh) ^ rsw) << 3;  // swizzled granule (shorts)
            short8 b0 = *(const short8*)&ldsB[cur][baseB0 + gx];
            short8 b1 = *(const short8*)&ldsB[cur][baseB1 + gx];
            if (ok0) {
                short8 a0 = *(const short8*)&ldsA[cur][baseA0 + gx];
                acc[0][0] = __builtin_amdgcn_mfma_f32_32x32x16_bf16(a0, b0, acc[0][0], 0, 0, 0);
                acc[0][1] = __builtin_amdgcn_mfma_f32_32x32x16_bf16(a0, b1, acc[0][1], 0, 0, 0);
            }
            if (ok1) {
                short8 a1 = *(const short8*)&ldsA[cur][baseA1 + gx];
                acc[1][0] = __builtin_amdgcn_mfma_f32_32x32x16_bf16(a1, b0, acc[1][0], 0, 0, 0);
                acc[1][1] = __builtin_amdgcn_mfma_f32_32x32x16_bf16(a1, b1, acc[1][1], 0, 0, 0);
            }
        }
        if (more) {
            store_to(cur ^ 1);
            __syncthreads();
        }
    }

    // epilogue: C/D layout col = lane&31, row = (reg&3) + 8*(reg>>2) + 4*(lane>>5)
    #pragma unroll
    for (int mi = 0; mi < 2; ++mi) {
        const int ro = rank0 + mi;
        if (ro < nranks) {
            const int s = wsi[WS_PERM + rank_base + ro];
            #pragma unroll
            for (int ni = 0; ni < 2; ++ni) {
                const int ocol = ntile * TN + wn + ni*32 + l31;
                #pragma unroll
                for (int r = 0; r < 16; ++r) {
                    const int brow = (r & 3) + 8*(r >> 2) + 4*lh;  // batch b
                    out[(((size_t)(brow * SEQ + s)) << 10) + ocol] = acc[mi][ni][r];
                }
            }
        }
    }
}

extern "C" void kernel_launch(void* const* d_in, const int* in_sizes, int n_in,
                              void* d_out, int out_size, void* d_ws, size_t ws_size,
                              hipStream_t stream) {
    const float* x         = (const float*)d_in[0];
    const int*   layer_idx = (const int*)  d_in[1];
    const float* weight    = (const float*)d_in[2];
    float* out = (float*)d_out;
    int*   wsi = (int*)d_ws;

    prep_kernel<<<1, 256, 0, stream>>>(layer_idx, wsi);
    gemm_kernel<<<512, THREADS, 0, stream>>>(x, weight, wsi, out);
}